// Round 7
// baseline (368.847 us; speedup 1.0000x reference)
//
#include <hip/hip_runtime.h>

typedef float f32x4 __attribute__((ext_vector_type(4)));
typedef float f32x16 __attribute__((ext_vector_type(16)));
typedef __bf16 bf16x8 __attribute__((ext_vector_type(8)));
typedef unsigned short u16x8 __attribute__((ext_vector_type(8)));

__device__ __forceinline__ unsigned short f2bf(float f) {
  union { float f; unsigned int u; } v; v.f = f;
  unsigned int u = v.u;
  unsigned int r = (u + 0x7FFFu + ((u >> 16) & 1u)) >> 16;  // RNE
  return (unsigned short)r;
}

// ---------------- cast x (f32 -> bf16), 8 elems/thread, grid-stride ----------------
__global__ __launch_bounds__(256) void k_cast_bf16(const float* __restrict__ in,
                                                   unsigned short* __restrict__ out, int n8) {
  const f32x4* p = (const f32x4*)in;
  for (int i = blockIdx.x * 256 + threadIdx.x; i < n8; i += 2048 * 256) {
    f32x4 a = p[2 * i], b = p[2 * i + 1];
    u16x8 o;
    o[0] = f2bf(a[0]); o[1] = f2bf(a[1]); o[2] = f2bf(a[2]); o[3] = f2bf(a[3]);
    o[4] = f2bf(b[0]); o[5] = f2bf(b[1]); o[6] = f2bf(b[2]); o[7] = f2bf(b[3]);
    ((u16x8*)out)[i] = o;
  }
}

// -------- Bw[o][e*16+r] = coeffs[e]*scales[e]*Bf[e][o][r], bf16 --------
__global__ void k_build_bw(const float* __restrict__ Bf,
                           const float* __restrict__ coeffs,
                           const float* __restrict__ scales,
                           unsigned short* __restrict__ bw) {
  int t = blockIdx.x * 256 + threadIdx.x;
  int o = t >> 8, k = t & 255, e = k >> 4, r = k & 15;
  float v = coeffs[e] * scales[e] * Bf[((size_t)e * 4096 + o) * 16 + r];
  bw[t] = f2bf(v);
}

// -------- At[d][e*16+r] = A[e][r][d], bf16, via LDS transpose --------
__global__ void k_build_at(const float* __restrict__ A,
                           unsigned short* __restrict__ at) {
  __shared__ float tile[64][65];
  int kt = blockIdx.x * 64, dt = blockIdx.y * 64;
  int tx = threadIdx.x & 63, ty = threadIdx.x >> 6;
#pragma unroll
  for (int j = 0; j < 64; j += 4)
    tile[ty + j][tx] = A[(size_t)(kt + ty + j) * 4096 + dt + tx];
  __syncthreads();
#pragma unroll
  for (int j = 0; j < 64; j += 4)
    at[(size_t)(dt + ty + j) * 256 + kt + tx] = f2bf(tile[tx][ty + j]);
}

// ------------- prep GEMM (m97 structure), W_eff = Bw @ At^T + W -------------
template <int M_, int N_, int K_>
__global__ __launch_bounds__(256) void k_gemm_prep(
    const unsigned short* __restrict__ Abuf,
    const unsigned short* __restrict__ Bbuf,
    const float* __restrict__ Wadd,
    unsigned short* __restrict__ outB) {
  constexpr int NBN = N_ / 128;
  constexpr int NWG = (M_ / 128) * NBN;
  const int bid = blockIdx.x;
  const int swz = (bid & 7) * (NWG / 8) + (bid >> 3);
  const int bm = swz / NBN, bn = swz % NBN;

  __shared__ unsigned short ldsA[128 * 64];
  __shared__ unsigned short ldsB[128 * 64];

  const int t = threadIdx.x, w = t >> 6, l = t & 63;
  const int wr = w >> 1, wc = w & 1;

  f32x4 acc[4][4] = {};
  const int m0 = bm * 128, n0 = bn * 128;
  const int srow = w * 8 + (l >> 3);
  const int scol = (l & 7) * 8;
  const unsigned short* gA = Abuf + (size_t)(m0 + srow) * K_ + scol;
  const unsigned short* gB = Bbuf + (size_t)(n0 + srow) * K_ + scol;

  for (int kt = 0; kt < K_; kt += 64) {
#pragma unroll
    for (int i = 0; i < 4; ++i) {
      __builtin_amdgcn_global_load_lds(
          (__attribute__((address_space(1))) void*)(gA + (size_t)i * 32 * K_ + kt),
          (__attribute__((address_space(3))) void*)(ldsA + i * 2048 + w * 512), 16, 0, 0);
      __builtin_amdgcn_global_load_lds(
          (__attribute__((address_space(1))) void*)(gB + (size_t)i * 32 * K_ + kt),
          (__attribute__((address_space(3))) void*)(ldsB + i * 2048 + w * 512), 16, 0, 0);
    }
    __syncthreads();
#pragma unroll
    for (int kk = 0; kk < 2; ++kk) {
      const int col = kk * 32 + (l >> 4) * 8;
      const int arow = wr * 64 + (l & 15);
      const int brow = wc * 64 + (l & 15);
      bf16x8 af[4], bfv[4];
#pragma unroll
      for (int mi = 0; mi < 4; ++mi)
        af[mi] = *(const bf16x8*)&ldsA[(arow + mi * 16) * 64 + col];
#pragma unroll
      for (int ni = 0; ni < 4; ++ni)
        bfv[ni] = *(const bf16x8*)&ldsB[(brow + ni * 16) * 64 + col];
#pragma unroll
      for (int mi = 0; mi < 4; ++mi)
#pragma unroll
        for (int ni = 0; ni < 4; ++ni)
          acc[mi][ni] = __builtin_amdgcn_mfma_f32_16x16x32_bf16(
              af[mi], bfv[ni], acc[mi][ni], 0, 0, 0);
    }
    __syncthreads();
  }

  const int mrow0 = m0 + wr * 64 + (l >> 4) * 4;
  const int ncol0 = n0 + wc * 64 + (l & 15);
#pragma unroll
  for (int mi = 0; mi < 4; ++mi)
#pragma unroll
    for (int r = 0; r < 4; ++r) {
      const int m = mrow0 + mi * 16 + r;
#pragma unroll
      for (int ni = 0; ni < 4; ++ni) {
        const int n = ncol0 + ni * 16;
        outB[(size_t)m * N_ + n] = f2bf(acc[mi][ni][r] + Wadd[(size_t)m * N_ + n]);
      }
    }
}

// ===== main GEMM: 256x256 tile, BK=32, 5-buf ring, 32x32x16 MFMA =====
// A [M_][K_] bf16, B [N_][K_] bf16, out f32 = A*B^T + bias.
// LDS 160 KiB = 5 bufs x 32 KiB (A [256][32] at +0, B at +16384).
// Swizzle: phys slot s at row r holds logical 16B block s ^ ((r>>1)&3);
// staging keeps LDS dest linear, pre-swizzles GLOBAL source (rule #21).
// 32x32x16 fragments: A row = l&31, k = (l>>5)*8 + j (8 contiguous bf16);
// logical block = kk*2 + (l>>5); bank-audit: 8 lanes x 16B per 4-bank group
// per b128 -> balanced, conflict-free. C/D (m74/m101): col = l&31,
// row = (reg&3) + 8*(reg>>2) + 4*(l>>5).
// Iter {t,t+1}: vmcnt(4) -> barrier -> reads(t) 12xb128 -> stage(t+3) ->
// 16 MFMA32 -> reads(t+1) -> stage(t+4) -> 16 MFMA32. 1 barrier / 2 K-tiles.
template <int M_, int N_, int K_>
__global__ __launch_bounds__(512, 2) void k_gemm256(
    const unsigned short* __restrict__ Abuf,
    const unsigned short* __restrict__ Bbuf,
    const float* __restrict__ bias,
    float* __restrict__ outF) {
  constexpr int NBN = N_ / 256;
  constexpr int NWG = (M_ / 256) * NBN;
  constexpr int NT = K_ / 32;
  static_assert(NWG % 8 == 0, "bijective xcd swizzle");
  static_assert(NT % 2 == 0 && NT >= 6, "pipeline depth");

  const int bid = blockIdx.x;
  const int swz = (bid & 7) * (NWG / 8) + (bid >> 3);
  const int bm = swz / NBN, bn = swz % NBN;
  const int m0 = bm * 256, n0 = bn * 256;

  __shared__ __attribute__((aligned(128))) unsigned short lds[81920];  // 160 KiB
  char* ldsb = (char*)lds;

  const int tid = threadIdx.x, w = tid >> 6, l = tid & 63;
  const int wr = w >> 2, wc = w & 3;  // 2 M-waves x 4 N-waves; per-wave 128x64

  // staging: instr i covers rows i*128 + w*16 + (l>>2); dest linear lane*16
  const int scol = ((l & 3) ^ ((l >> 3) & 3)) * 8;
  const unsigned short* gA = Abuf + (size_t)(m0 + w * 16 + (l >> 2)) * K_ + scol;
  const unsigned short* gB = Bbuf + (size_t)(n0 + w * 16 + (l >> 2)) * K_ + scol;
  const int dA = w * 1024;            // + buf*32768 + i*8192
  const int dB = 16384 + w * 1024;

  // fragment reads (32x32): row = base + (l&31); phys slot(kk) = (kk*2+(l>>5)) ^ ((l>>1)&3)
  int qk[2];
  qk[0] = (((l >> 5) ^ ((l >> 1) & 3)) << 4);
  qk[1] = (((2 + (l >> 5)) ^ ((l >> 1) & 3)) << 4);
  const int raOff = (wr * 128 + (l & 31)) * 64;           // + mi*2048 + qk[kk]
  const int rbOff = 16384 + (wc * 64 + (l & 31)) * 64;    // + ni*2048 + qk[kk]

  f32x16 acc[4][2] = {};

#define STAGE_T(tt, bf)                                                               \
  do {                                                                                \
    const int bb_ = (bf) * 32768;                                                     \
    const size_t ko_ = (size_t)(tt) * 32;                                             \
    _Pragma("unroll") for (int i_ = 0; i_ < 2; ++i_) {                                \
      __builtin_amdgcn_global_load_lds(                                               \
          (__attribute__((address_space(1))) void*)(gA + (size_t)i_ * 128 * K_ + ko_),\
          (__attribute__((address_space(3))) void*)(ldsb + bb_ + i_ * 8192 + dA),     \
          16, 0, 0);                                                                  \
      __builtin_amdgcn_global_load_lds(                                               \
          (__attribute__((address_space(1))) void*)(gB + (size_t)i_ * 128 * K_ + ko_),\
          (__attribute__((address_space(3))) void*)(ldsb + bb_ + i_ * 8192 + dB),     \
          16, 0, 0);                                                                  \
    }                                                                                 \
  } while (0)

#define RD_A(mi, kk, bf) \
  (*(const bf16x8*)(ldsb + (bf) * 32768 + raOff + (mi) * 2048 + qk[kk]))
#define RD_B(ni, kk, bf) \
  (*(const bf16x8*)(ldsb + (bf) * 32768 + rbOff + (ni) * 2048 + qk[kk]))

  // prologue: stage tiles 0,1,2 into bufs 0,1,2 (12 loads in flight)
  STAGE_T(0, 0); STAGE_T(1, 1); STAGE_T(2, 2);

  int bT = 0;  // buf index of tile tt (tt % 5)
  for (int tt = 0; tt < NT; tt += 2) {
    const int b0 = bT;
    const int b1 = (bT + 1 >= 5) ? bT + 1 - 5 : bT + 1;
    const int s3 = (bT + 3 >= 5) ? bT + 3 - 5 : bT + 3;
    const int s4 = (bT + 4 >= 5) ? bT + 4 - 5 : bT + 4;

    // drain tiles tt, tt+1 (issued a full iteration ago); keep tt+2 in flight
    if (tt + 2 < NT) asm volatile("s_waitcnt vmcnt(4)" ::: "memory");
    else             asm volatile("s_waitcnt vmcnt(0)" ::: "memory");
    __builtin_amdgcn_s_barrier();
    __builtin_amdgcn_sched_barrier(0);

    // ---- tile tt ----
    bf16x8 a[4][2], b[2][2];
#pragma unroll
    for (int kk = 0; kk < 2; ++kk) {
#pragma unroll
      for (int mi = 0; mi < 4; ++mi) a[mi][kk] = RD_A(mi, kk, b0);
#pragma unroll
      for (int ni = 0; ni < 2; ++ni) b[ni][kk] = RD_B(ni, kk, b0);
    }
    if (tt + 3 < NT) STAGE_T(tt + 3, s3);

    __builtin_amdgcn_s_setprio(1);
#pragma unroll
    for (int kk = 0; kk < 2; ++kk)
#pragma unroll
      for (int mi = 0; mi < 4; ++mi)
#pragma unroll
        for (int ni = 0; ni < 2; ++ni)
          acc[mi][ni] = __builtin_amdgcn_mfma_f32_32x32x16_bf16(
              a[mi][kk], b[ni][kk], acc[mi][ni], 0, 0, 0);
    __builtin_amdgcn_s_setprio(0);

    // ---- tile tt+1 ----
    bf16x8 c[4][2], u[2][2];
#pragma unroll
    for (int kk = 0; kk < 2; ++kk) {
#pragma unroll
      for (int mi = 0; mi < 4; ++mi) c[mi][kk] = RD_A(mi, kk, b1);
#pragma unroll
      for (int ni = 0; ni < 2; ++ni) u[ni][kk] = RD_B(ni, kk, b1);
    }
    if (tt + 4 < NT) STAGE_T(tt + 4, s4);

    __builtin_amdgcn_s_setprio(1);
#pragma unroll
    for (int kk = 0; kk < 2; ++kk)
#pragma unroll
      for (int mi = 0; mi < 4; ++mi)
#pragma unroll
        for (int ni = 0; ni < 2; ++ni)
          acc[mi][ni] = __builtin_amdgcn_mfma_f32_32x32x16_bf16(
              c[mi][kk], u[ni][kk], acc[mi][ni], 0, 0, 0);
    __builtin_amdgcn_s_setprio(0);

    bT += 2; if (bT >= 5) bT -= 5;
  }
#undef STAGE_T
#undef RD_A
#undef RD_B

  // epilogue: C/D layout col = l&31, row = (reg&3) + 8*(reg>>2) + 4*(l>>5)
#pragma unroll
  for (int ni = 0; ni < 2; ++ni) {
    const int n = n0 + wc * 64 + ni * 32 + (l & 31);
    const float bv2 = bias[n];
#pragma unroll
    for (int mi = 0; mi < 4; ++mi) {
      const int mbase = m0 + wr * 128 + mi * 32 + 4 * (l >> 5);
#pragma unroll
      for (int reg = 0; reg < 16; ++reg) {
        const int m = mbase + (reg & 3) + 8 * (reg >> 2);
        outF[(size_t)m * N_ + n] = acc[mi][ni][reg] + bv2;
      }
    }
  }
}

extern "C" void kernel_launch(void* const* d_in, const int* in_sizes, int n_in,
                              void* d_out, int out_size, void* d_ws, size_t ws_size,
                              hipStream_t stream) {
  const float* x      = (const float*)d_in[0];
  const float* W      = (const float*)d_in[1];
  const float* bias   = (const float*)d_in[2];
  const float* A      = (const float*)d_in[3];
  const float* Bf     = (const float*)d_in[4];
  const float* coeffs = (const float*)d_in[5];
  const float* scales = (const float*)d_in[6];
  float* out = (float*)d_out;

  char* ws = (char*)d_ws;
  unsigned short* xb   = (unsigned short*)(ws);
  unsigned short* weff = (unsigned short*)(ws + 67108864);
  unsigned short* bw   = (unsigned short*)(ws + 67108864 + 33554432);
  unsigned short* at   = (unsigned short*)(ws + 67108864 + 33554432 + 2097152);

  k_cast_bf16<<<2048, 256, 0, stream>>>(x, xb, (8192 * 4096) / 8);
  k_build_bw<<<4096, 256, 0, stream>>>(Bf, coeffs, scales, bw);
  k_build_at<<<dim3(4, 64), 256, 0, stream>>>(A, at);
  k_gemm_prep<4096, 4096, 256><<<1024, 256, 0, stream>>>(bw, at, W, weff);
  k_gemm256<8192, 4096, 4096><<<512, 512, 0, stream>>>(xb, weff, bias, out);
}

// Round 8
// 352.333 us; speedup vs baseline: 1.0469x; 1.0469x over previous
//
#include <hip/hip_runtime.h>

typedef float f32x4 __attribute__((ext_vector_type(4)));
typedef __bf16 bf16x8 __attribute__((ext_vector_type(8)));
typedef unsigned short u16x8 __attribute__((ext_vector_type(8)));

__device__ __forceinline__ unsigned short f2bf(float f) {
  union { float f; unsigned int u; } v; v.f = f;
  unsigned int u = v.u;
  unsigned int r = (u + 0x7FFFu + ((u >> 16) & 1u)) >> 16;  // RNE
  return (unsigned short)r;
}

// ---------------- cast x (f32 -> bf16), 8 elems/thread, grid-stride ----------------
__global__ __launch_bounds__(256) void k_cast_bf16(const float* __restrict__ in,
                                                   unsigned short* __restrict__ out, int n8) {
  const f32x4* p = (const f32x4*)in;
  for (int i = blockIdx.x * 256 + threadIdx.x; i < n8; i += 2048 * 256) {
    f32x4 a = p[2 * i], b = p[2 * i + 1];
    u16x8 o;
    o[0] = f2bf(a[0]); o[1] = f2bf(a[1]); o[2] = f2bf(a[2]); o[3] = f2bf(a[3]);
    o[4] = f2bf(b[0]); o[5] = f2bf(b[1]); o[6] = f2bf(b[2]); o[7] = f2bf(b[3]);
    ((u16x8*)out)[i] = o;
  }
}

// -------- Bw[o][e*16+r] = coeffs[e]*scales[e]*Bf[e][o][r], bf16 --------
__global__ void k_build_bw(const float* __restrict__ Bf,
                           const float* __restrict__ coeffs,
                           const float* __restrict__ scales,
                           unsigned short* __restrict__ bw) {
  int t = blockIdx.x * 256 + threadIdx.x;
  int o = t >> 8, k = t & 255, e = k >> 4, r = k & 15;
  float v = coeffs[e] * scales[e] * Bf[((size_t)e * 4096 + o) * 16 + r];
  bw[t] = f2bf(v);
}

// -------- At[d][e*16+r] = A[e][r][d], bf16, via LDS transpose --------
__global__ void k_build_at(const float* __restrict__ A,
                           unsigned short* __restrict__ at) {
  __shared__ float tile[64][65];
  int kt = blockIdx.x * 64, dt = blockIdx.y * 64;
  int tx = threadIdx.x & 63, ty = threadIdx.x >> 6;
#pragma unroll
  for (int j = 0; j < 64; j += 4)
    tile[ty + j][tx] = A[(size_t)(kt + ty + j) * 4096 + dt + tx];
  __syncthreads();
#pragma unroll
  for (int j = 0; j < 64; j += 4)
    at[(size_t)(dt + ty + j) * 256 + kt + tx] = f2bf(tile[tx][ty + j]);
}

// ------------- prep GEMM (m97 structure), W_eff = Bw @ At^T + W -------------
template <int M_, int N_, int K_>
__global__ __launch_bounds__(256) void k_gemm_prep(
    const unsigned short* __restrict__ Abuf,
    const unsigned short* __restrict__ Bbuf,
    const float* __restrict__ Wadd,
    unsigned short* __restrict__ outB) {
  constexpr int NBN = N_ / 128;
  constexpr int NWG = (M_ / 128) * NBN;
  const int bid = blockIdx.x;
  const int swz = (bid & 7) * (NWG / 8) + (bid >> 3);
  const int bm = swz / NBN, bn = swz % NBN;

  __shared__ unsigned short ldsA[128 * 64];
  __shared__ unsigned short ldsB[128 * 64];

  const int t = threadIdx.x, w = t >> 6, l = t & 63;
  const int wr = w >> 1, wc = w & 1;

  f32x4 acc[4][4] = {};
  const int m0 = bm * 128, n0 = bn * 128;
  const int srow = w * 8 + (l >> 3);
  const int scol = (l & 7) * 8;
  const unsigned short* gA = Abuf + (size_t)(m0 + srow) * K_ + scol;
  const unsigned short* gB = Bbuf + (size_t)(n0 + srow) * K_ + scol;

  for (int kt = 0; kt < K_; kt += 64) {
#pragma unroll
    for (int i = 0; i < 4; ++i) {
      __builtin_amdgcn_global_load_lds(
          (__attribute__((address_space(1))) void*)(gA + (size_t)i * 32 * K_ + kt),
          (__attribute__((address_space(3))) void*)(ldsA + i * 2048 + w * 512), 16, 0, 0);
      __builtin_amdgcn_global_load_lds(
          (__attribute__((address_space(1))) void*)(gB + (size_t)i * 32 * K_ + kt),
          (__attribute__((address_space(3))) void*)(ldsB + i * 2048 + w * 512), 16, 0, 0);
    }
    __syncthreads();
#pragma unroll
    for (int kk = 0; kk < 2; ++kk) {
      const int col = kk * 32 + (l >> 4) * 8;
      const int arow = wr * 64 + (l & 15);
      const int brow = wc * 64 + (l & 15);
      bf16x8 af[4], bfv[4];
#pragma unroll
      for (int mi = 0; mi < 4; ++mi)
        af[mi] = *(const bf16x8*)&ldsA[(arow + mi * 16) * 64 + col];
#pragma unroll
      for (int ni = 0; ni < 4; ++ni)
        bfv[ni] = *(const bf16x8*)&ldsB[(brow + ni * 16) * 64 + col];
#pragma unroll
      for (int mi = 0; mi < 4; ++mi)
#pragma unroll
        for (int ni = 0; ni < 4; ++ni)
          acc[mi][ni] = __builtin_amdgcn_mfma_f32_16x16x32_bf16(
              af[mi], bfv[ni], acc[mi][ni], 0, 0, 0);
    }
    __syncthreads();
  }

  const int mrow0 = m0 + wr * 64 + (l >> 4) * 4;
  const int ncol0 = n0 + wc * 64 + (l & 15);
#pragma unroll
  for (int mi = 0; mi < 4; ++mi)
#pragma unroll
    for (int r = 0; r < 4; ++r) {
      const int m = mrow0 + mi * 16 + r;
#pragma unroll
      for (int ni = 0; ni < 4; ++ni) {
        const int n = ncol0 + ni * 16;
        outB[(size_t)m * N_ + n] = f2bf(acc[mi][ni][r] + Wadd[(size_t)m * N_ + n]);
      }
    }
}

// ===== main GEMM: 256x256 tile, BK=32, 5-buf ring, wave-parity anti-phase =====
// A [M_][K_] bf16, B [N_][K_] bf16, out f32 = A*B^T + bias.
// LDS 160 KiB = 5 bufs x 32 KiB (A [256][32] at +0, B at +16384).
// Swizzle (0-conflict, verified R3/R6): phys slot s at row r holds logical 16B
// block s ^ ((r>>1)&3); staging keeps LDS dest linear, pre-swizzles the GLOBAL
// source block (rule #21): lane fetches block (l&3)^((l>>3)&3).
// Iter {tt,tt+1}: vmcnt(4) proves BOTH tiles landed (outstanding=12 ->
// drain 8 oldest = tt,tt+1; keep tt+2). Then EVEN waves process tt,tt+1 and
// ODD waves process tt+1,tt -> at any instant half the waves are in their
// ds_read burst while the other half are in their MFMA burst: LDS and MFMA
// pipes run concurrently instead of alternately (the 1-wg/CU barrier group
// has no independent blocks to overlap with, so we anti-phase internally).
// Stage targets tt+3,tt+4 are outside {tt,tt+1} in the ring-5 (safe for both
// orders); per-wave stage issue order is identical (vmcnt math unchanged).
template <int M_, int N_, int K_>
__global__ __launch_bounds__(512, 2) void k_gemm256(
    const unsigned short* __restrict__ Abuf,
    const unsigned short* __restrict__ Bbuf,
    const float* __restrict__ bias,
    float* __restrict__ outF) {
  constexpr int NBN = N_ / 256;
  constexpr int NWG = (M_ / 256) * NBN;
  constexpr int NT = K_ / 32;
  static_assert(NWG % 8 == 0, "bijective xcd swizzle");
  static_assert(NT % 2 == 0 && NT >= 6, "pipeline depth");

  const int bid = blockIdx.x;
  const int swz = (bid & 7) * (NWG / 8) + (bid >> 3);
  const int bm = swz / NBN, bn = swz % NBN;
  const int m0 = bm * 256, n0 = bn * 256;

  __shared__ __attribute__((aligned(128))) unsigned short lds[81920];  // 160 KiB
  char* ldsb = (char*)lds;

  const int tid = threadIdx.x, w = tid >> 6, l = tid & 63;
  const int wr = w >> 2, wc = w & 3;  // 2 M-waves x 4 N-waves; per-wave 128x64

  // staging: instr i covers rows i*128 + w*16 + (l>>2); dest linear lane*16
  const int scol = ((l & 3) ^ ((l >> 3) & 3)) * 8;
  const unsigned short* gA = Abuf + (size_t)(m0 + w * 16 + (l >> 2)) * K_ + scol;
  const unsigned short* gB = Bbuf + (size_t)(n0 + w * 16 + (l >> 2)) * K_ + scol;
  const int dA = w * 1024;            // + buf*32768 + i*8192
  const int dB = 16384 + w * 1024;

  // fragment reads: row = base + (l&15); phys slot = (l>>4) ^ ((row>>1)&3)
  const int qp = ((l >> 4) ^ ((l >> 1) & 3)) << 4;
  const int raOff = (wr * 128 + (l & 15)) * 64 + qp;           // + mi*1024
  const int rbOff = 16384 + (wc * 64 + (l & 15)) * 64 + qp;    // + ni*1024

  f32x4 acc[8][4] = {};

#define STAGE_T(tt, bf)                                                               \
  do {                                                                                \
    const int bb_ = (bf) * 32768;                                                     \
    const size_t ko_ = (size_t)(tt) * 32;                                             \
    _Pragma("unroll") for (int i_ = 0; i_ < 2; ++i_) {                                \
      __builtin_amdgcn_global_load_lds(                                               \
          (__attribute__((address_space(1))) void*)(gA + (size_t)i_ * 128 * K_ + ko_),\
          (__attribute__((address_space(3))) void*)(ldsb + bb_ + i_ * 8192 + dA),     \
          16, 0, 0);                                                                  \
      __builtin_amdgcn_global_load_lds(                                               \
          (__attribute__((address_space(1))) void*)(gB + (size_t)i_ * 128 * K_ + ko_),\
          (__attribute__((address_space(3))) void*)(ldsb + bb_ + i_ * 8192 + dB),     \
          16, 0, 0);                                                                  \
    }                                                                                 \
  } while (0)

#define RD_A(mi, bf) (*(const bf16x8*)(ldsb + (bf) * 32768 + raOff + (mi) * 1024))
#define RD_B(ni, bf) (*(const bf16x8*)(ldsb + (bf) * 32768 + rbOff + (ni) * 1024))

// one K-tile: 12 ds_read_b128 -> optional stage -> 32 MFMA (setprio-wrapped)
#define TILE_BODY(bf, stg_t, stg_b, do_stg)                                           \
  do {                                                                                \
    bf16x8 fa0 = RD_A(0, bf), fa1 = RD_A(1, bf), fa2 = RD_A(2, bf), fa3 = RD_A(3, bf);\
    bf16x8 fa4 = RD_A(4, bf), fa5 = RD_A(5, bf), fa6 = RD_A(6, bf), fa7 = RD_A(7, bf);\
    bf16x8 fb0 = RD_B(0, bf), fb1 = RD_B(1, bf), fb2 = RD_B(2, bf), fb3 = RD_B(3, bf);\
    if (do_stg) STAGE_T(stg_t, stg_b);                                                \
    __builtin_amdgcn_s_setprio(1);                                                    \
    _Pragma("unroll") for (int ni_ = 0; ni_ < 4; ++ni_) {                             \
      bf16x8 vv = (ni_ == 0) ? fb0 : (ni_ == 1) ? fb1 : (ni_ == 2) ? fb2 : fb3;       \
      acc[0][ni_] = __builtin_amdgcn_mfma_f32_16x16x32_bf16(fa0, vv, acc[0][ni_], 0, 0, 0); \
      acc[1][ni_] = __builtin_amdgcn_mfma_f32_16x16x32_bf16(fa1, vv, acc[1][ni_], 0, 0, 0); \
      acc[2][ni_] = __builtin_amdgcn_mfma_f32_16x16x32_bf16(fa2, vv, acc[2][ni_], 0, 0, 0); \
      acc[3][ni_] = __builtin_amdgcn_mfma_f32_16x16x32_bf16(fa3, vv, acc[3][ni_], 0, 0, 0); \
      acc[4][ni_] = __builtin_amdgcn_mfma_f32_16x16x32_bf16(fa4, vv, acc[4][ni_], 0, 0, 0); \
      acc[5][ni_] = __builtin_amdgcn_mfma_f32_16x16x32_bf16(fa5, vv, acc[5][ni_], 0, 0, 0); \
      acc[6][ni_] = __builtin_amdgcn_mfma_f32_16x16x32_bf16(fa6, vv, acc[6][ni_], 0, 0, 0); \
      acc[7][ni_] = __builtin_amdgcn_mfma_f32_16x16x32_bf16(fa7, vv, acc[7][ni_], 0, 0, 0); \
    }                                                                                 \
    __builtin_amdgcn_s_setprio(0);                                                    \
  } while (0)

  // prologue: stage tiles 0,1,2 into bufs 0,1,2 (12 loads in flight)
  STAGE_T(0, 0); STAGE_T(1, 1); STAGE_T(2, 2);

  int bT = 0;  // buf index of tile tt (tt % 5)
  for (int tt = 0; tt < NT; tt += 2) {
    const int b0 = bT;
    const int b1 = (bT + 1 >= 5) ? bT + 1 - 5 : bT + 1;
    const int s3 = (bT + 3 >= 5) ? bT + 3 - 5 : bT + 3;
    const int s4 = (bT + 4 >= 5) ? bT + 4 - 5 : bT + 4;
    const bool st3 = (tt + 3) < NT, st4 = (tt + 4) < NT;

    // drain tiles tt, tt+1 (issued a full iteration ago); keep tt+2 in flight
    if (tt + 2 < NT) asm volatile("s_waitcnt vmcnt(4)" ::: "memory");
    else             asm volatile("s_waitcnt vmcnt(0)" ::: "memory");
    __builtin_amdgcn_s_barrier();
    __builtin_amdgcn_sched_barrier(0);

    if ((w & 1) == 0) {
      TILE_BODY(b0, tt + 3, s3, st3);
      TILE_BODY(b1, tt + 4, s4, st4);
    } else {
      TILE_BODY(b1, tt + 3, s3, st3);
      TILE_BODY(b0, tt + 4, s4, st4);
    }

    bT += 2; if (bT >= 5) bT -= 5;
  }
#undef STAGE_T
#undef RD_A
#undef RD_B
#undef TILE_BODY

  // epilogue: C/D layout col = lane&15, row = (lane>>4)*4 + reg
#pragma unroll
  for (int ni = 0; ni < 4; ++ni) {
    const int n = n0 + wc * 64 + ni * 16 + (l & 15);
    const float bv2 = bias[n];
#pragma unroll
    for (int mi = 0; mi < 8; ++mi) {
      const int m = m0 + wr * 128 + mi * 16 + (l >> 4) * 4;
#pragma unroll
      for (int r = 0; r < 4; ++r)
        outF[(size_t)(m + r) * N_ + n] = acc[mi][ni][r] + bv2;
    }
  }
}

extern "C" void kernel_launch(void* const* d_in, const int* in_sizes, int n_in,
                              void* d_out, int out_size, void* d_ws, size_t ws_size,
                              hipStream_t stream) {
  const float* x      = (const float*)d_in[0];
  const float* W      = (const float*)d_in[1];
  const float* bias   = (const float*)d_in[2];
  const float* A      = (const float*)d_in[3];
  const float* Bf     = (const float*)d_in[4];
  const float* coeffs = (const float*)d_in[5];
  const float* scales = (const float*)d_in[6];
  float* out = (float*)d_out;

  char* ws = (char*)d_ws;
  unsigned short* xb   = (unsigned short*)(ws);
  unsigned short* weff = (unsigned short*)(ws + 67108864);
  unsigned short* bw   = (unsigned short*)(ws + 67108864 + 33554432);
  unsigned short* at   = (unsigned short*)(ws + 67108864 + 33554432 + 2097152);

  k_cast_bf16<<<2048, 256, 0, stream>>>(x, xb, (8192 * 4096) / 8);
  k_build_bw<<<4096, 256, 0, stream>>>(Bf, coeffs, scales, bw);
  k_build_at<<<dim3(4, 64), 256, 0, stream>>>(A, at);
  k_gemm_prep<4096, 4096, 256><<<1024, 256, 0, stream>>>(bw, at, W, weff);
  k_gemm256<8192, 4096, 4096><<<512, 512, 0, stream>>>(xb, weff, bias, out);
}

// Round 9
// 352.330 us; speedup vs baseline: 1.0469x; 1.0000x over previous
//
#include <hip/hip_runtime.h>

typedef float f32x4 __attribute__((ext_vector_type(4)));
typedef __bf16 bf16x8 __attribute__((ext_vector_type(8)));
typedef unsigned short u16x8 __attribute__((ext_vector_type(8)));

__device__ __forceinline__ unsigned short f2bf(float f) {
  union { float f; unsigned int u; } v; v.f = f;
  unsigned int u = v.u;
  unsigned int r = (u + 0x7FFFu + ((u >> 16) & 1u)) >> 16;  // RNE
  return (unsigned short)r;
}

// ---------------- cast x (f32 -> bf16), 8 elems/thread, grid-stride ----------------
__global__ __launch_bounds__(256) void k_cast_bf16(const float* __restrict__ in,
                                                   unsigned short* __restrict__ out, int n8) {
  const f32x4* p = (const f32x4*)in;
  for (int i = blockIdx.x * 256 + threadIdx.x; i < n8; i += 2048 * 256) {
    f32x4 a = p[2 * i], b = p[2 * i + 1];
    u16x8 o;
    o[0] = f2bf(a[0]); o[1] = f2bf(a[1]); o[2] = f2bf(a[2]); o[3] = f2bf(a[3]);
    o[4] = f2bf(b[0]); o[5] = f2bf(b[1]); o[6] = f2bf(b[2]); o[7] = f2bf(b[3]);
    ((u16x8*)out)[i] = o;
  }
}

// -------- Bw[o][e*16+r] = coeffs[e]*scales[e]*Bf[e][o][r], bf16 --------
__global__ void k_build_bw(const float* __restrict__ Bf,
                           const float* __restrict__ coeffs,
                           const float* __restrict__ scales,
                           unsigned short* __restrict__ bw) {
  int t = blockIdx.x * 256 + threadIdx.x;
  int o = t >> 8, k = t & 255, e = k >> 4, r = k & 15;
  float v = coeffs[e] * scales[e] * Bf[((size_t)e * 4096 + o) * 16 + r];
  bw[t] = f2bf(v);
}

// -------- At[d][e*16+r] = A[e][r][d], bf16, via LDS transpose --------
__global__ void k_build_at(const float* __restrict__ A,
                           unsigned short* __restrict__ at) {
  __shared__ float tile[64][65];
  int kt = blockIdx.x * 64, dt = blockIdx.y * 64;
  int tx = threadIdx.x & 63, ty = threadIdx.x >> 6;
#pragma unroll
  for (int j = 0; j < 64; j += 4)
    tile[ty + j][tx] = A[(size_t)(kt + ty + j) * 4096 + dt + tx];
  __syncthreads();
#pragma unroll
  for (int j = 0; j < 64; j += 4)
    at[(size_t)(dt + ty + j) * 256 + kt + tx] = f2bf(tile[tx][ty + j]);
}

// ------------- prep GEMM (m97 structure), W_eff = Bw @ At^T + W -------------
template <int M_, int N_, int K_>
__global__ __launch_bounds__(256) void k_gemm_prep(
    const unsigned short* __restrict__ Abuf,
    const unsigned short* __restrict__ Bbuf,
    const float* __restrict__ Wadd,
    unsigned short* __restrict__ outB) {
  constexpr int NBN = N_ / 128;
  constexpr int NWG = (M_ / 128) * NBN;
  const int bid = blockIdx.x;
  const int swz = (bid & 7) * (NWG / 8) + (bid >> 3);
  const int bm = swz / NBN, bn = swz % NBN;

  __shared__ unsigned short ldsA[128 * 64];
  __shared__ unsigned short ldsB[128 * 64];

  const int t = threadIdx.x, w = t >> 6, l = t & 63;
  const int wr = w >> 1, wc = w & 1;

  f32x4 acc[4][4] = {};
  const int m0 = bm * 128, n0 = bn * 128;
  const int srow = w * 8 + (l >> 3);
  const int scol = (l & 7) * 8;
  const unsigned short* gA = Abuf + (size_t)(m0 + srow) * K_ + scol;
  const unsigned short* gB = Bbuf + (size_t)(n0 + srow) * K_ + scol;

  for (int kt = 0; kt < K_; kt += 64) {
#pragma unroll
    for (int i = 0; i < 4; ++i) {
      __builtin_amdgcn_global_load_lds(
          (__attribute__((address_space(1))) void*)(gA + (size_t)i * 32 * K_ + kt),
          (__attribute__((address_space(3))) void*)(ldsA + i * 2048 + w * 512), 16, 0, 0);
      __builtin_amdgcn_global_load_lds(
          (__attribute__((address_space(1))) void*)(gB + (size_t)i * 32 * K_ + kt),
          (__attribute__((address_space(3))) void*)(ldsB + i * 2048 + w * 512), 16, 0, 0);
    }
    __syncthreads();
#pragma unroll
    for (int kk = 0; kk < 2; ++kk) {
      const int col = kk * 32 + (l >> 4) * 8;
      const int arow = wr * 64 + (l & 15);
      const int brow = wc * 64 + (l & 15);
      bf16x8 af[4], bfv[4];
#pragma unroll
      for (int mi = 0; mi < 4; ++mi)
        af[mi] = *(const bf16x8*)&ldsA[(arow + mi * 16) * 64 + col];
#pragma unroll
      for (int ni = 0; ni < 4; ++ni)
        bfv[ni] = *(const bf16x8*)&ldsB[(brow + ni * 16) * 64 + col];
#pragma unroll
      for (int mi = 0; mi < 4; ++mi)
#pragma unroll
        for (int ni = 0; ni < 4; ++ni)
          acc[mi][ni] = __builtin_amdgcn_mfma_f32_16x16x32_bf16(
              af[mi], bfv[ni], acc[mi][ni], 0, 0, 0);
    }
    __syncthreads();
  }

  const int mrow0 = m0 + wr * 64 + (l >> 4) * 4;
  const int ncol0 = n0 + wc * 64 + (l & 15);
#pragma unroll
  for (int mi = 0; mi < 4; ++mi)
#pragma unroll
    for (int r = 0; r < 4; ++r) {
      const int m = mrow0 + mi * 16 + r;
#pragma unroll
      for (int ni = 0; ni < 4; ++ni) {
        const int n = ncol0 + ni * 16;
        outB[(size_t)m * N_ + n] = f2bf(acc[mi][ni][r] + Wadd[(size_t)m * N_ + n]);
      }
    }
}

// ===== main GEMM: 256x256 tile, BK=32, 5-buf ring, intra-SIMD anti-phase =====
// A [M_][K_] bf16, B [N_][K_] bf16, out f32 = A*B^T + bias.
// LDS 160 KiB = 5 bufs x 32 KiB (A [256][32] at +0, B at +16384).
// Swizzle (0-conflict, verified R3/R6): phys slot s at row r holds logical 16B
// block s ^ ((r>>1)&3); staging keeps LDS dest linear, pre-swizzles the GLOBAL
// source block (rule #21): lane fetches block (l&3)^((l>>3)&3).
// Iter {tt,tt+1}: vmcnt(4) proves BOTH tiles landed. Waves with parity
// p(w)=((w>>2)^w)&1 == 0 process tt then tt+1; p==1 process tt+1 then tt.
// p() yields OPPOSITE parity for the two waves co-resident on each SIMD under
// both wid%4 (pairs {0,4},{1,5},..) and wid/2 (pairs {0,1},{2,3},..) mappings
// -- R8's w&1 gave SAME parity per SIMD under wid%4, nullifying the lever.
// Result: on every SIMD, one wave's ds_read burst overlaps the other wave's
// MFMA burst; LDS and MFMA pipes run concurrently instead of alternately.
// Stage targets tt+3,tt+4 are outside {tt,tt+1} in the ring-5 (safe both
// orders); per-wave stage issue order identical (vmcnt math unchanged).
template <int M_, int N_, int K_>
__global__ __launch_bounds__(512, 2) void k_gemm256(
    const unsigned short* __restrict__ Abuf,
    const unsigned short* __restrict__ Bbuf,
    const float* __restrict__ bias,
    float* __restrict__ outF) {
  constexpr int NBN = N_ / 256;
  constexpr int NWG = (M_ / 256) * NBN;
  constexpr int NT = K_ / 32;
  static_assert(NWG % 8 == 0, "bijective xcd swizzle");
  static_assert(NT % 2 == 0 && NT >= 6, "pipeline depth");

  const int bid = blockIdx.x;
  const int swz = (bid & 7) * (NWG / 8) + (bid >> 3);
  const int bm = swz / NBN, bn = swz % NBN;
  const int m0 = bm * 256, n0 = bn * 256;

  __shared__ __attribute__((aligned(128))) unsigned short lds[81920];  // 160 KiB
  char* ldsb = (char*)lds;

  const int tid = threadIdx.x, w = tid >> 6, l = tid & 63;
  const int wr = w >> 2, wc = w & 3;  // 2 M-waves x 4 N-waves; per-wave 128x64

  // staging: instr i covers rows i*128 + w*16 + (l>>2); dest linear lane*16
  const int scol = ((l & 3) ^ ((l >> 3) & 3)) * 8;
  const unsigned short* gA = Abuf + (size_t)(m0 + w * 16 + (l >> 2)) * K_ + scol;
  const unsigned short* gB = Bbuf + (size_t)(n0 + w * 16 + (l >> 2)) * K_ + scol;
  const int dA = w * 1024;            // + buf*32768 + i*8192
  const int dB = 16384 + w * 1024;

  // fragment reads: row = base + (l&15); phys slot = (l>>4) ^ ((row>>1)&3)
  const int qp = ((l >> 4) ^ ((l >> 1) & 3)) << 4;
  const int raOff = (wr * 128 + (l & 15)) * 64 + qp;           // + mi*1024
  const int rbOff = 16384 + (wc * 64 + (l & 15)) * 64 + qp;    // + ni*1024

  f32x4 acc[8][4] = {};

#define STAGE_T(tt, bf)                                                               \
  do {                                                                                \
    const int bb_ = (bf) * 32768;                                                     \
    const size_t ko_ = (size_t)(tt) * 32;                                             \
    _Pragma("unroll") for (int i_ = 0; i_ < 2; ++i_) {                                \
      __builtin_amdgcn_global_load_lds(                                               \
          (__attribute__((address_space(1))) void*)(gA + (size_t)i_ * 128 * K_ + ko_),\
          (__attribute__((address_space(3))) void*)(ldsb + bb_ + i_ * 8192 + dA),     \
          16, 0, 0);                                                                  \
      __builtin_amdgcn_global_load_lds(                                               \
          (__attribute__((address_space(1))) void*)(gB + (size_t)i_ * 128 * K_ + ko_),\
          (__attribute__((address_space(3))) void*)(ldsb + bb_ + i_ * 8192 + dB),     \
          16, 0, 0);                                                                  \
    }                                                                                 \
  } while (0)

#define RD_A(mi, bf) (*(const bf16x8*)(ldsb + (bf) * 32768 + raOff + (mi) * 1024))
#define RD_B(ni, bf) (*(const bf16x8*)(ldsb + (bf) * 32768 + rbOff + (ni) * 1024))

// one K-tile: 12 ds_read_b128 -> optional stage -> 32 MFMA (setprio-wrapped)
#define TILE_BODY(bf, stg_t, stg_b, do_stg)                                           \
  do {                                                                                \
    bf16x8 fa0 = RD_A(0, bf), fa1 = RD_A(1, bf), fa2 = RD_A(2, bf), fa3 = RD_A(3, bf);\
    bf16x8 fa4 = RD_A(4, bf), fa5 = RD_A(5, bf), fa6 = RD_A(6, bf), fa7 = RD_A(7, bf);\
    bf16x8 fb0 = RD_B(0, bf), fb1 = RD_B(1, bf), fb2 = RD_B(2, bf), fb3 = RD_B(3, bf);\
    if (do_stg) STAGE_T(stg_t, stg_b);                                                \
    __builtin_amdgcn_s_setprio(1);                                                    \
    _Pragma("unroll") for (int ni_ = 0; ni_ < 4; ++ni_) {                             \
      bf16x8 vv = (ni_ == 0) ? fb0 : (ni_ == 1) ? fb1 : (ni_ == 2) ? fb2 : fb3;       \
      acc[0][ni_] = __builtin_amdgcn_mfma_f32_16x16x32_bf16(fa0, vv, acc[0][ni_], 0, 0, 0); \
      acc[1][ni_] = __builtin_amdgcn_mfma_f32_16x16x32_bf16(fa1, vv, acc[1][ni_], 0, 0, 0); \
      acc[2][ni_] = __builtin_amdgcn_mfma_f32_16x16x32_bf16(fa2, vv, acc[2][ni_], 0, 0, 0); \
      acc[3][ni_] = __builtin_amdgcn_mfma_f32_16x16x32_bf16(fa3, vv, acc[3][ni_], 0, 0, 0); \
      acc[4][ni_] = __builtin_amdgcn_mfma_f32_16x16x32_bf16(fa4, vv, acc[4][ni_], 0, 0, 0); \
      acc[5][ni_] = __builtin_amdgcn_mfma_f32_16x16x32_bf16(fa5, vv, acc[5][ni_], 0, 0, 0); \
      acc[6][ni_] = __builtin_amdgcn_mfma_f32_16x16x32_bf16(fa6, vv, acc[6][ni_], 0, 0, 0); \
      acc[7][ni_] = __builtin_amdgcn_mfma_f32_16x16x32_bf16(fa7, vv, acc[7][ni_], 0, 0, 0); \
    }                                                                                 \
    __builtin_amdgcn_s_setprio(0);                                                    \
  } while (0)

  // prologue: stage tiles 0,1,2 into bufs 0,1,2 (12 loads in flight)
  STAGE_T(0, 0); STAGE_T(1, 1); STAGE_T(2, 2);

  const bool phaseA = (((w >> 2) ^ w) & 1) == 0;  // mixed per SIMD (see header)

  int bT = 0;  // buf index of tile tt (tt % 5)
  for (int tt = 0; tt < NT; tt += 2) {
    const int b0 = bT;
    const int b1 = (bT + 1 >= 5) ? bT + 1 - 5 : bT + 1;
    const int s3 = (bT + 3 >= 5) ? bT + 3 - 5 : bT + 3;
    const int s4 = (bT + 4 >= 5) ? bT + 4 - 5 : bT + 4;
    const bool st3 = (tt + 3) < NT, st4 = (tt + 4) < NT;

    // drain tiles tt, tt+1 (issued a full iteration ago); keep tt+2 in flight
    if (tt + 2 < NT) asm volatile("s_waitcnt vmcnt(4)" ::: "memory");
    else             asm volatile("s_waitcnt vmcnt(0)" ::: "memory");
    __builtin_amdgcn_s_barrier();
    __builtin_amdgcn_sched_barrier(0);

    if (phaseA) {
      TILE_BODY(b0, tt + 3, s3, st3);
      TILE_BODY(b1, tt + 4, s4, st4);
    } else {
      TILE_BODY(b1, tt + 3, s3, st3);
      TILE_BODY(b0, tt + 4, s4, st4);
    }

    bT += 2; if (bT >= 5) bT -= 5;
  }
#undef STAGE_T
#undef RD_A
#undef RD_B
#undef TILE_BODY

  // epilogue: C/D layout col = lane&15, row = (lane>>4)*4 + reg
#pragma unroll
  for (int ni = 0; ni < 4; ++ni) {
    const int n = n0 + wc * 64 + ni * 16 + (l & 15);
    const float bv2 = bias[n];
#pragma unroll
    for (int mi = 0; mi < 8; ++mi) {
      const int m = m0 + wr * 128 + mi * 16 + (l >> 4) * 4;
#pragma unroll
      for (int r = 0; r < 4; ++r)
        outF[(size_t)(m + r) * N_ + n] = acc[mi][ni][r] + bv2;
    }
  }
}

extern "C" void kernel_launch(void* const* d_in, const int* in_sizes, int n_in,
                              void* d_out, int out_size, void* d_ws, size_t ws_size,
                              hipStream_t stream) {
  const float* x      = (const float*)d_in[0];
  const float* W      = (const float*)d_in[1];
  const float* bias   = (const float*)d_in[2];
  const float* A      = (const float*)d_in[3];
  const float* Bf     = (const float*)d_in[4];
  const float* coeffs = (const float*)d_in[5];
  const float* scales = (const float*)d_in[6];
  float* out = (float*)d_out;

  char* ws = (char*)d_ws;
  unsigned short* xb   = (unsigned short*)(ws);
  unsigned short* weff = (unsigned short*)(ws + 67108864);
  unsigned short* bw   = (unsigned short*)(ws + 67108864 + 33554432);
  unsigned short* at   = (unsigned short*)(ws + 67108864 + 33554432 + 2097152);

  k_cast_bf16<<<2048, 256, 0, stream>>>(x, xb, (8192 * 4096) / 8);
  k_build_bw<<<4096, 256, 0, stream>>>(Bf, coeffs, scales, bw);
  k_build_at<<<dim3(4, 64), 256, 0, stream>>>(A, at);
  k_gemm_prep<4096, 4096, 256><<<1024, 256, 0, stream>>>(bw, at, W, weff);
  k_gemm256<8192, 4096, 4096><<<512, 512, 0, stream>>>(xb, weff, bias, out);
}